// Round 4
// baseline (400.965 us; speedup 1.0000x reference)
//
#include <hip/hip_runtime.h>
#include <stdint.h>

// ---------------------------------------------------------------------------
// SelfAttention: B=4, S=2048, E=1024 (single head)
// R12 algebra: scores = Xq·Wq^T·Wk·Xk^T = NT(q'', Xk) with
//   Mp[t,k] = sum_o Wk[o,t]*Wq[o,k]   (1024x1024, fp32-FMA, computed by 1024
//             side-blocks INSIDE the cvt dispatch -- reads fp32 weights only,
//             overlaps cvt's BW-bound streaming on idle VALU pipes)
//   q''     = NT(Xq, Mp)              (replaces q-projection)
// This DELETES the k-projection GEMM (17.2 GF) and the kb buffer; scores
// reads Xk (bf16 raw keys) directly. proj: 1536 -> 1024 blocks (perfect 4/CU).
//   vT = Wv @ Xv^T  (unchanged);  P = exp(q'' Xk^T / 32);  out = P v / rowsum
// ---------------------------------------------------------------------------

typedef __attribute__((ext_vector_type(8))) short short8;       // 8 x bf16 frag
typedef __attribute__((ext_vector_type(4))) float floatx4;      // MFMA acc
typedef __attribute__((ext_vector_type(4))) unsigned short u16x4;
typedef __attribute__((ext_vector_type(4))) float f32x4v;
typedef __attribute__((ext_vector_type(2))) float f32x2v;

__device__ __forceinline__ unsigned short f32_to_bf16(float f) {
    union { float f; unsigned u; } c; c.f = f;
    unsigned u = c.u;
    return (unsigned short)((u + 0x7fffu + ((u >> 16) & 1u)) >> 16);  // RNE
}

#define G2L(g, l) __builtin_amdgcn_global_load_lds( \
    (__attribute__((address_space(1))) void*)(void*)(g), \
    (__attribute__((address_space(3))) void*)(l), 16, 0, 0)

#define BAR() __builtin_amdgcn_s_barrier()

// ---- cvt dispatch: bf16 converts (3x X, Wv) + rowsum zero + Mp side-GEMM --
// grid: 25608 convert blocks + 1024 Mp blocks (32x32 tiles, fp32 FMA).
#define CVT_BLOCKS 25608

__global__ __launch_bounds__(256) void cvt_all(
    const float* __restrict__ q, const float* __restrict__ k,
    const float* __restrict__ v, const float* __restrict__ wq,
    const float* __restrict__ wk, const float* __restrict__ wv,
    unsigned short* __restrict__ Xq, unsigned short* __restrict__ Xk,
    unsigned short* __restrict__ Xv, unsigned short* __restrict__ Wv,
    unsigned short* __restrict__ Mp, float* __restrict__ rowsum) {
    __shared__ float Ao[32][36];
    __shared__ float Bo[32][36];

    if (blockIdx.x >= CVT_BLOCKS) {
        // ---- Mp[t,k] = sum_o Wk[o, t] * Wq[o, k] ----  (32x32 tile/block)
        const int id = blockIdx.x - CVT_BLOCKS;   // 0..1023
        const int t0 = (id >> 5) * 32;
        const int k0 = (id & 31) * 32;
        const int tx = threadIdx.x & 15;          // 16x16 thread grid, 2x2 acc
        const int ty = threadIdx.x >> 4;
        const int sr = threadIdx.x >> 3;          // stage row 0..31
        const int sc = (threadIdx.x & 7) * 4;     // stage col (float4)
        float a00 = 0.f, a01 = 0.f, a10 = 0.f, a11 = 0.f;
        for (int o0 = 0; o0 < 1024; o0 += 32) {
            *(f32x4v*)&Ao[sr][sc] =
                *(const f32x4v*)&wk[(size_t)(o0 + sr) * 1024 + t0 + sc];
            *(f32x4v*)&Bo[sr][sc] =
                *(const f32x4v*)&wq[(size_t)(o0 + sr) * 1024 + k0 + sc];
            __syncthreads();
#pragma unroll
            for (int o = 0; o < 32; ++o) {
                const f32x2v av = *(const f32x2v*)&Ao[o][tx * 2];
                const f32x2v bv = *(const f32x2v*)&Bo[o][ty * 2];
                a00 += av[0] * bv[0]; a01 += av[0] * bv[1];
                a10 += av[1] * bv[0]; a11 += av[1] * bv[1];
            }
            __syncthreads();
        }
        const int t = t0 + tx * 2, kk = k0 + ty * 2;
        Mp[(size_t)t * 1024 + kk]           = f32_to_bf16(a00);
        Mp[(size_t)t * 1024 + kk + 1]       = f32_to_bf16(a01);
        Mp[(size_t)(t + 1) * 1024 + kk]     = f32_to_bf16(a10);
        Mp[(size_t)(t + 1) * 1024 + kk + 1] = f32_to_bf16(a11);
        return;
    }

    const long NTE4 = 2097152;  // 8192*1024/4
    const long NW4  = 262144;   // 1024*1024/4
    long i = (long)blockIdx.x * 256 + threadIdx.x;
    const float* src;
    unsigned short* dst;
    long j;
    if (i < 3 * NTE4) {
        int a = (int)(i / NTE4); j = i - (long)a * NTE4;
        src = a == 0 ? q : a == 1 ? k : v;
        dst = a == 0 ? Xq : a == 1 ? Xk : Xv;
    } else {
        i -= 3 * NTE4;
        if (i < NW4) {
            src = wv; dst = Wv; j = i;
        } else {
            i -= NW4;           // 2048 groups -> rowsum[0..8191] = 0
            if (i < 2048) ((f32x4v*)rowsum)[i] = (f32x4v)0.0f;
            return;
        }
    }
    f32x4v f = ((const f32x4v*)src)[j];
    u16x4 o;
#pragma unroll
    for (int t = 0; t < 4; ++t) o[t] = f32_to_bf16(f[t]);
    ((u16x4*)dst)[j] = o;
}

// ===========================================================================
// 128x128 body (proj + pv: 4 blocks/CU co-resident, proven 942 TF structure)
// ===========================================================================
#define BM 128
#define BN 128
#define BK 64

// EPI: 0 = store bf16; 2 = store fp32 x / rowsum[row]
template <int EPI>
__device__ __forceinline__ void gemm_body(
    const unsigned short* __restrict__ A, const unsigned short* __restrict__ B,
    void* __restrict__ Cv, int lda, int ldb, int ldc, int K, float scale,
    float* __restrict__ rowsum, int m0, int n0) {
    __shared__ unsigned short As[BM * BK];
    __shared__ unsigned short Bs[BN * BK];

    const int tid  = threadIdx.x;
    const int wave = tid >> 6;
    const int lane = tid & 63;
    const int lm   = lane & 15;
    const int quad = lane >> 4;
    const int wm   = wave >> 1;
    const int wn   = wave & 1;

    const int srow8 = lane >> 3;
    const int gcol  = ((lane & 7) ^ srow8) * 8;

    floatx4 acc[4][4];
#pragma unroll
    for (int i = 0; i < 4; ++i)
#pragma unroll
        for (int j = 0; j < 4; ++j) acc[i][j] = (floatx4)0.0f;

    for (int k0 = 0; k0 < K; k0 += BK) {
#pragma unroll
        for (int i = 0; i < 4; ++i) {
            const int rbase = wave * 32 + i * 8;
            G2L(A + (size_t)(m0 + rbase + srow8) * lda + k0 + gcol,
                &As[rbase * BK]);
            G2L(B + (size_t)(n0 + rbase + srow8) * ldb + k0 + gcol,
                &Bs[rbase * BK]);
        }
        __syncthreads();

#pragma unroll
        for (int s = 0; s < 2; ++s) {
            short8 af[4], bf[4];
#pragma unroll
            for (int t = 0; t < 4; ++t) {
                const int cs = ((s * 4 + quad) ^ (lm & 7)) * 8;
                af[t] = *(const short8*)&As[(wm * 64 + t * 16 + lm) * BK + cs];
                bf[t] = *(const short8*)&Bs[(wn * 64 + t * 16 + lm) * BK + cs];
            }
#pragma unroll
            for (int mt = 0; mt < 4; ++mt)
#pragma unroll
                for (int nt = 0; nt < 4; ++nt)
                    acc[mt][nt] = __builtin_amdgcn_mfma_f32_16x16x32_bf16(
                        af[mt], bf[nt], acc[mt][nt], 0, 0, 0);
        }
        __syncthreads();
    }

    // epilogue: D row = quad*4 + reg, col = lane&15 (m89/m91 mapping)
    if constexpr (EPI == 0) {
        unsigned short* C = (unsigned short*)Cv;
#pragma unroll
        for (int mt = 0; mt < 4; ++mt)
#pragma unroll
            for (int nt = 0; nt < 4; ++nt)
#pragma unroll
                for (int r = 0; r < 4; ++r) {
                    const int row = m0 + wm * 64 + mt * 16 + quad * 4 + r;
                    const int col = n0 + wn * 64 + nt * 16 + lm;
                    C[(size_t)row * ldc + col] = f32_to_bf16(acc[mt][nt][r]);
                }
    } else if constexpr (EPI == 2) {
        float* C = (float*)Cv;
#pragma unroll
        for (int mt = 0; mt < 4; ++mt)
#pragma unroll
            for (int r = 0; r < 4; ++r) {
                const int row = m0 + wm * 64 + mt * 16 + quad * 4 + r;
                const float inv = 1.0f / rowsum[row];
#pragma unroll
                for (int nt = 0; nt < 4; ++nt) {
                    const int col = n0 + wn * 64 + nt * 16 + lm;
                    C[(size_t)row * ldc + col] = acc[mt][nt][r] * inv;
                }
            }
    }
}

// ---- merged projections: z=0 q''=Xq@Mp^T ; z=1 vT=Wv@Xv^T (roles swapped) -
__global__ __launch_bounds__(256, 4) void proj_kernel(
    const unsigned short* __restrict__ Xq, const unsigned short* __restrict__ Mp,
    unsigned short* __restrict__ qb,
    const unsigned short* __restrict__ Wv, const unsigned short* __restrict__ Xv,
    unsigned short* __restrict__ vT) {
    const int z = blockIdx.z;
    const unsigned short* A = z == 0 ? Xq : Wv;
    const unsigned short* B = z == 0 ? Mp : Xv;
    unsigned short* C = z == 0 ? qb : vT;
    int m0, n0, ldc;
    if (z == 0) { m0 = blockIdx.x * BM; n0 = blockIdx.y * BN; ldc = 1024; }
    else        { m0 = blockIdx.y * BM; n0 = blockIdx.x * BN; ldc = 8192; }
    gemm_body<0>(A, B, C, 1024, 1024, ldc, 1024, 1.0f, nullptr, m0, n0);
}

__global__ __launch_bounds__(256, 4) void pv_kernel(
    const unsigned short* __restrict__ Sc, const unsigned short* __restrict__ vT,
    float* __restrict__ out, float* __restrict__ rowsum) {
    const long z = blockIdx.z;
    gemm_body<2>(Sc + z * 2048 * 2048, vT + z * 2048,
                 out + z * 2048 * 1024, 2048, 8192, 1024, 2048,
                 1.0f, rowsum + z * 2048,
                 blockIdx.x * BM, blockIdx.y * BN);
}

// ===========================================================================
// 256x256 8-phase body (scores only: 256 blocks = perfect 1/CU packing)
// ===========================================================================
template <int EPI>
__device__ __forceinline__ void gemm256_body(
    const unsigned short* __restrict__ A, const unsigned short* __restrict__ B,
    void* __restrict__ Cv, int lda, int ldb, int ldc, int K, float scale,
    float* __restrict__ rowsum, int m0, int n0) {
    __shared__ unsigned short As[2][256 * 64];
    __shared__ unsigned short Bs[2][256 * 64];

    const int tid   = threadIdx.x;
    const int wave  = tid >> 6;      // 0..7
    const int lane  = tid & 63;
    const int lm    = lane & 15;     // MFMA row-in-frag
    const int quad  = lane >> 4;     // 0..3
    const int wm    = wave >> 2;     // 0..1  (wave tile 2x4)
    const int wn    = wave & 3;      // 0..3
    const int srow8 = lane >> 3;
    const int gcol  = ((lane & 7) ^ srow8) * 8;  // pre-swizzled global col
    const int KT    = K >> 6;

#define STAGE_A(buf, half, kcol) do { \
        const int r0_ = (half) * 128 + wave * 8; \
        G2L(A + (size_t)(m0 + r0_ + srow8) * lda + (kcol) + gcol, \
            &As[buf][r0_ * 64]); \
        G2L(A + (size_t)(m0 + r0_ + 64 + srow8) * lda + (kcol) + gcol, \
            &As[buf][(r0_ + 64) * 64]); \
    } while (0)
#define STAGE_B(buf, half, kcol) do { \
        const int r0_ = (half) * 128 + wave * 8; \
        G2L(B + (size_t)(n0 + r0_ + srow8) * ldb + (kcol) + gcol, \
            &Bs[buf][r0_ * 64]); \
        G2L(B + (size_t)(n0 + r0_ + 64 + srow8) * ldb + (kcol) + gcol, \
            &Bs[buf][(r0_ + 64) * 64]); \
    } while (0)

    floatx4 acc[8][4];
#pragma unroll
    for (int i = 0; i < 8; ++i)
#pragma unroll
        for (int j = 0; j < 4; ++j) acc[i][j] = (floatx4)0.0f;

    // prologue: tile0 -> buf0, tile1 -> buf1 (8 loads each); vmcnt(8) => t0 landed
    STAGE_A(0, 0, 0); STAGE_A(0, 1, 0); STAGE_B(0, 0, 0); STAGE_B(0, 1, 0);
    if (KT > 1) {
        STAGE_A(1, 0, 64); STAGE_A(1, 1, 64);
        STAGE_B(1, 0, 64); STAGE_B(1, 1, 64);
        asm volatile("s_waitcnt vmcnt(8)" ::: "memory");
    } else {
        asm volatile("s_waitcnt vmcnt(0)" ::: "memory");
    }
    BAR();

    short8 aA[2][4];   // A half m0  (Q1, Q4)
    short8 aM[2][4];   // A half m1  (Q2, Q3)
    short8 bB[2][2];   // B half: n0 during Q1/Q2, overwritten with n1 at S3

    for (int kt = 0; kt < KT; ++kt) {
        const int b = kt & 1;
        const unsigned short* Ab = As[b];
        const unsigned short* Bb = Bs[b];

        // ---- S1: reads for Q1 (aA + bB=n0), then read-ahead aM (Q2) ----
#pragma unroll
        for (int s = 0; s < 2; ++s) {
            const int cs = ((s * 4 + quad) ^ (lm & 7)) * 8;
#pragma unroll
            for (int mt = 0; mt < 4; ++mt)
                aA[s][mt] = *(const short8*)&Ab[(wm * 128 + mt * 16 + lm) * 64 + cs];
#pragma unroll
            for (int nt = 0; nt < 2; ++nt)
                bB[s][nt] = *(const short8*)&Bb[(wn * 64 + nt * 16 + lm) * 64 + cs];
        }
#pragma unroll
        for (int s = 0; s < 2; ++s) {
            const int cs = ((s * 4 + quad) ^ (lm & 7)) * 8;
#pragma unroll
            for (int mt = 0; mt < 4; ++mt)
                aM[s][mt] = *(const short8*)&Ab[(wm * 128 + 64 + mt * 16 + lm) * 64 + cs];
        }
        BAR();
        // P1: MFMA Q1 (compiler waits counted lgkm; aM stays in flight)
        __builtin_amdgcn_s_setprio(1);
#pragma unroll
        for (int s = 0; s < 2; ++s)
#pragma unroll
            for (int mt = 0; mt < 4; ++mt)
#pragma unroll
                for (int nt = 0; nt < 2; ++nt)
                    acc[mt][nt] = __builtin_amdgcn_mfma_f32_16x16x32_bf16(
                        aA[s][mt], bB[s][nt], acc[mt][nt], 0, 0, 0);
        __builtin_amdgcn_s_setprio(0);
        BAR();

        // ---- S2: (no reads, no stages) ----
        BAR();
        // P2: MFMA Q2
        __builtin_amdgcn_s_setprio(1);
#pragma unroll
        for (int s = 0; s < 2; ++s)
#pragma unroll
            for (int mt = 0; mt < 4; ++mt)
#pragma unroll
                for (int nt = 0; nt < 2; ++nt)
                    acc[4 + mt][nt] = __builtin_amdgcn_mfma_f32_16x16x32_bf16(
                        aM[s][mt], bB[s][nt], acc[4 + mt][nt], 0, 0, 0);
        __builtin_amdgcn_s_setprio(0);
        BAR();

        // ---- S3: read bB=n1 (A-reads all done by P2-close); stage A(t+2) ----
#pragma unroll
        for (int s = 0; s < 2; ++s) {
            const int cs = ((s * 4 + quad) ^ (lm & 7)) * 8;
#pragma unroll
            for (int nt = 0; nt < 2; ++nt)
                bB[s][nt] = *(const short8*)&Bb[(wn * 64 + 32 + nt * 16 + lm) * 64 + cs];
        }
        if (kt + 2 < KT) { STAGE_A(b, 0, (kt + 2) * 64); STAGE_A(b, 1, (kt + 2) * 64); }
        BAR();
        // P3: MFMA Q3
        __builtin_amdgcn_s_setprio(1);
#pragma unroll
        for (int s = 0; s < 2; ++s)
#pragma unroll
            for (int mt = 0; mt < 4; ++mt)
#pragma unroll
                for (int nt = 0; nt < 2; ++nt)
                    acc[4 + mt][2 + nt] = __builtin_amdgcn_mfma_f32_16x16x32_bf16(
                        aM[s][mt], bB[s][nt], acc[4 + mt][2 + nt], 0, 0, 0);
        __builtin_amdgcn_s_setprio(0);
        BAR();

        // ---- S4: stage B(t+2) (B-reads all done by P3-close) ----
        if (kt + 2 < KT) { STAGE_B(b, 0, (kt + 2) * 64); STAGE_B(b, 1, (kt + 2) * 64); }
        BAR();
        // P4: MFMA Q4; then counted vmcnt => tile t+1 landed; publish barrier
        __builtin_amdgcn_s_setprio(1);
#pragma unroll
        for (int s = 0; s < 2; ++s)
#pragma unroll
            for (int mt = 0; mt < 4; ++mt)
#pragma unroll
                for (int nt = 0; nt < 2; ++nt)
                    acc[mt][2 + nt] = __builtin_amdgcn_mfma_f32_16x16x32_bf16(
                        aA[s][mt], bB[s][nt], acc[mt][2 + nt], 0, 0, 0);
        __builtin_amdgcn_s_setprio(0);
        if (kt + 2 < KT) {
            asm volatile("s_waitcnt vmcnt(8)" ::: "memory");
        } else if (kt + 1 < KT) {
            asm volatile("s_waitcnt vmcnt(0)" ::: "memory");
        }
        BAR();
    }
#undef STAGE_A
#undef STAGE_B

    // epilogue: D row = quad*4 + reg, col = lane&15 (m89/m91 mapping)
    if constexpr (EPI == 1) {
        unsigned short* C = (unsigned short*)Cv;
        float psum[8][4];
#pragma unroll
        for (int f = 0; f < 8; ++f)
#pragma unroll
            for (int r = 0; r < 4; ++r) psum[f][r] = 0.0f;
#pragma unroll
        for (int f = 0; f < 8; ++f)
#pragma unroll
            for (int g = 0; g < 4; ++g)
#pragma unroll
                for (int r = 0; r < 4; ++r) {
                    const int row = m0 + wm * 128 + f * 16 + quad * 4 + r;
                    const int col = n0 + wn * 64 + g * 16 + lm;
                    const float p = __expf(acc[f][g][r] * scale);
                    psum[f][r] += p;
                    C[(size_t)row * ldc + col] = f32_to_bf16(p);
                }
#pragma unroll
        for (int off = 1; off <= 8; off <<= 1)
#pragma unroll
            for (int f = 0; f < 8; ++f)
#pragma unroll
                for (int r = 0; r < 4; ++r)
                    psum[f][r] += __shfl_xor(psum[f][r], off);
        if (lm == 0) {
#pragma unroll
            for (int f = 0; f < 8; ++f)
#pragma unroll
                for (int r = 0; r < 4; ++r)
                    atomicAdd(&rowsum[m0 + wm * 128 + f * 16 + quad * 4 + r],
                              psum[f][r]);
        }
    }
}

__global__ __launch_bounds__(512, 2) void scores256_kernel(
    const unsigned short* __restrict__ qb, const unsigned short* __restrict__ Xk,
    unsigned short* __restrict__ Sc, float* __restrict__ rowsum) {
    const long z = blockIdx.z;
    gemm256_body<1>(qb + z * 2048 * 1024, Xk + z * 2048 * 1024,
                    Sc + z * 2048 * 2048, 1024, 1024, 2048, 1024,
                    1.0f / 32.0f, rowsum + z * 2048,
                    blockIdx.x * 256, blockIdx.y * 256);
}

// ---------------------------------------------------------------------------
extern "C" void kernel_launch(void* const* d_in, const int* in_sizes, int n_in,
                              void* d_out, int out_size, void* d_ws, size_t ws_size,
                              hipStream_t stream) {
    const float* q_in = (const float*)d_in[0];
    const float* k_in = (const float*)d_in[1];
    const float* v_in = (const float*)d_in[2];
    const float* Qw_f = (const float*)d_in[3];
    const float* Kw_f = (const float*)d_in[4];
    const float* Vw_f = (const float*)d_in[5];
    float* out = (float*)d_out;

    const int Bb = 4, S = 2048, E = 1024;
    const size_t TOK = (size_t)Bb * S;       // 8192
    const size_t NTE = TOK * E;              // 8,388,608
    const size_t NW  = (size_t)E * E;        // 1,048,576

    unsigned short* ws = (unsigned short*)d_ws;
    unsigned short* Xq = ws;            // [8192,1024]
    unsigned short* Xk = Xq + NTE;
    unsigned short* Xv = Xk + NTE;
    unsigned short* Wv = Xv + NTE;      // [1024,1024]
    unsigned short* Mp = Wv + NW;       // [1024 t][1024 k] = Wq^T Wk (transposed)
    unsigned short* qb = Mp + NW;       // [8192,1024]  q'' = Xq @ Mp^T
    unsigned short* vT = qb + NTE;      // [1024 e][8192 tok]
    unsigned short* Sc = vT + NTE;      // [4][2048][2048] exp-scores
    float* rowsum = (float*)(Sc + (size_t)Bb * S * S);  // [4][2048]

    // 1) converts (3 X + Wv) + rowsum zero + Mp side-GEMM, one dispatch
    cvt_all<<<CVT_BLOCKS + 1024, 256, 0, stream>>>(
        q_in, k_in, v_in, Qw_f, Kw_f, Vw_f,
        Xq, Xk, Xv, Wv, Mp, rowsum);

    // 2) q'' and vT, one dispatch (1024 blocks = perfect 4/CU packing)
    proj_kernel<<<dim3(TOK / BM, E / BN, 2), 256, 0, stream>>>(
        Xq, Mp, qb, Wv, Xv, vT);

    // 3) P = exp(q'' Xk^T / 32) + fp32 rowsums (256 blocks, perfect packing)
    scores256_kernel<<<dim3(S / 256, S / 256, 4), 512, 0, stream>>>(
        qb, Xk, Sc, rowsum);

    // 4) out = (P @ v) / rowsum  (128^2 body, 512 blocks, 4/CU)
    pv_kernel<<<dim3(S / BM, E / BN, 4), 256, 0, stream>>>(
        Sc, vT, out, rowsum);
}

// Round 5
// 330.322 us; speedup vs baseline: 1.2139x; 1.2139x over previous
//
#include <hip/hip_runtime.h>
#include <stdint.h>

// ---------------------------------------------------------------------------
// SelfAttention: B=4, S=2048, E=1024 (single head)
// R13 algebra (validated in R12): scores = Xq·Wq^T·Wk·Xk^T = NT(q'', Xk) with
//   Mp[t,k] = sum_o Wk[o,t]*Wq[o,k]  (1024x1024)
//   q''     = NT(Xq, Mp)             (replaces q-projection; k-proj DELETED)
// R13 fix: Mp via MFMA, not fp32 VALU (R12's fp32 side-GEMM = 2.1 GF of
// vector-fp32 -> 130us tail; no fp32 MFMA on CDNA4). cvt now emits
// transposed split-precision weights WkTc=[Hk|Lk|Hk], WqTc=[Hq|Hq|Lq]
// (H=bf16(w), L=bf16(w-H)); mp_kernel = 64-block 128^2 MFMA GEMM over
// K=3072 -> Mp = (Hk+Lk)^T(Hq+Lq) - Lk^T Lq ~ fp32-accurate, rounded once.
//   vT = Wv @ Xv^T;  P = exp(q'' Xk^T / 32);  out = P v / rowsum
// ---------------------------------------------------------------------------

typedef __attribute__((ext_vector_type(8))) short short8;       // 8 x bf16 frag
typedef __attribute__((ext_vector_type(4))) float floatx4;      // MFMA acc
typedef __attribute__((ext_vector_type(4))) unsigned short u16x4;
typedef __attribute__((ext_vector_type(4))) float f32x4v;

__device__ __forceinline__ unsigned short f32_to_bf16(float f) {
    union { float f; unsigned u; } c; c.f = f;
    unsigned u = c.u;
    return (unsigned short)((u + 0x7fffu + ((u >> 16) & 1u)) >> 16);  // RNE
}

#define G2L(g, l) __builtin_amdgcn_global_load_lds( \
    (__attribute__((address_space(1))) void*)(void*)(g), \
    (__attribute__((address_space(3))) void*)(l), 16, 0, 0)

#define BAR() __builtin_amdgcn_s_barrier()

// ---- cvt dispatch: bf16 converts (3X + Wv) + rowsum zero + W transposes --
// grid: 25608 convert blocks + 512 transpose blocks (64x64 tiles, H/L split).
#define CVT_BLOCKS 25608
#define TR_BLOCKS 512

__global__ __launch_bounds__(256) void cvt_all(
    const float* __restrict__ q, const float* __restrict__ k,
    const float* __restrict__ v, const float* __restrict__ wq,
    const float* __restrict__ wk, const float* __restrict__ wv,
    unsigned short* __restrict__ Xq, unsigned short* __restrict__ Xk,
    unsigned short* __restrict__ Xv, unsigned short* __restrict__ Wv,
    unsigned short* __restrict__ WkTc, unsigned short* __restrict__ WqTc,
    float* __restrict__ rowsum) {
    __shared__ unsigned int Tt[64][65];   // packed (L<<16)|H, transposed tile

    if (blockIdx.x >= CVT_BLOCKS) {
        // ---- transpose-convert: out[c][o-cat] from in[o][c], 64x64 tile ----
        const int id  = (int)blockIdx.x - CVT_BLOCKS;  // 0..511
        const int mat = id >> 8;          // 0: wk -> WkTc [H|L|H]; 1: wq -> WqTc [H|H|L]
        const int tl  = id & 255;
        const int R0r = (tl >> 4) * 64;   // input row (o) block
        const int C0  = (tl & 15) * 64;   // input col (t/k) block
        const float* src = mat == 0 ? wk : wq;
        unsigned short* dst = mat == 0 ? WkTc : WqTc;
        const int rr = threadIdx.x >> 4;          // 0..15
        const int c4 = (threadIdx.x & 15) * 4;
#pragma unroll
        for (int p = 0; p < 4; ++p) {
            const int r = p * 16 + rr;
            const f32x4v v4 =
                *(const f32x4v*)&src[(size_t)(R0r + r) * 1024 + C0 + c4];
#pragma unroll
            for (int j = 0; j < 4; ++j) {
                const unsigned short h = f32_to_bf16(v4[j]);
                union { unsigned u; float f; } hf; hf.u = (unsigned)h << 16;
                const unsigned short l = f32_to_bf16(v4[j] - hf.f);
                Tt[c4 + j][r] = ((unsigned)l << 16) | (unsigned)h;
            }
        }
        __syncthreads();
#pragma unroll
        for (int p = 0; p < 4; ++p) {
            const int c = p * 16 + rr;
            u16x4 hv, lv;
#pragma unroll
            for (int j = 0; j < 4; ++j) {
                const unsigned w = Tt[c][c4 + j];
                hv[j] = (unsigned short)(w & 0xffffu);
                lv[j] = (unsigned short)(w >> 16);
            }
            unsigned short* o0 = dst + (size_t)(C0 + c) * 3072 + R0r + c4;
            *(u16x4*)(o0)        = hv;
            *(u16x4*)(o0 + 1024) = (mat == 0) ? lv : hv;
            *(u16x4*)(o0 + 2048) = (mat == 0) ? hv : lv;
        }
        return;
    }

    const long NTE4 = 2097152;  // 8192*1024/4
    const long NW4  = 262144;   // 1024*1024/4
    long i = (long)blockIdx.x * 256 + threadIdx.x;
    const float* src;
    unsigned short* dst;
    long j;
    if (i < 3 * NTE4) {
        int a = (int)(i / NTE4); j = i - (long)a * NTE4;
        src = a == 0 ? q : a == 1 ? k : v;
        dst = a == 0 ? Xq : a == 1 ? Xk : Xv;
    } else {
        i -= 3 * NTE4;
        if (i < NW4) {
            src = wv; dst = Wv; j = i;
        } else {
            i -= NW4;           // 2048 groups -> rowsum[0..8191] = 0
            if (i < 2048) ((f32x4v*)rowsum)[i] = (f32x4v)0.0f;
            return;
        }
    }
    f32x4v f = ((const f32x4v*)src)[j];
    u16x4 o;
#pragma unroll
    for (int t = 0; t < 4; ++t) o[t] = f32_to_bf16(f[t]);
    ((u16x4*)dst)[j] = o;
}

// ===========================================================================
// 128x128 body (mp + proj + pv: proven 942 TF structure)
// ===========================================================================
#define BM 128
#define BN 128
#define BK 64

// EPI: 0 = store bf16; 2 = store fp32 x / rowsum[row]
template <int EPI>
__device__ __forceinline__ void gemm_body(
    const unsigned short* __restrict__ A, const unsigned short* __restrict__ B,
    void* __restrict__ Cv, int lda, int ldb, int ldc, int K, float scale,
    float* __restrict__ rowsum, int m0, int n0) {
    __shared__ unsigned short As[BM * BK];
    __shared__ unsigned short Bs[BN * BK];

    const int tid  = threadIdx.x;
    const int wave = tid >> 6;
    const int lane = tid & 63;
    const int lm   = lane & 15;
    const int quad = lane >> 4;
    const int wm   = wave >> 1;
    const int wn   = wave & 1;

    const int srow8 = lane >> 3;
    const int gcol  = ((lane & 7) ^ srow8) * 8;

    floatx4 acc[4][4];
#pragma unroll
    for (int i = 0; i < 4; ++i)
#pragma unroll
        for (int j = 0; j < 4; ++j) acc[i][j] = (floatx4)0.0f;

    for (int k0 = 0; k0 < K; k0 += BK) {
#pragma unroll
        for (int i = 0; i < 4; ++i) {
            const int rbase = wave * 32 + i * 8;
            G2L(A + (size_t)(m0 + rbase + srow8) * lda + k0 + gcol,
                &As[rbase * BK]);
            G2L(B + (size_t)(n0 + rbase + srow8) * ldb + k0 + gcol,
                &Bs[rbase * BK]);
        }
        __syncthreads();

#pragma unroll
        for (int s = 0; s < 2; ++s) {
            short8 af[4], bf[4];
#pragma unroll
            for (int t = 0; t < 4; ++t) {
                const int cs = ((s * 4 + quad) ^ (lm & 7)) * 8;
                af[t] = *(const short8*)&As[(wm * 64 + t * 16 + lm) * BK + cs];
                bf[t] = *(const short8*)&Bs[(wn * 64 + t * 16 + lm) * BK + cs];
            }
#pragma unroll
            for (int mt = 0; mt < 4; ++mt)
#pragma unroll
                for (int nt = 0; nt < 4; ++nt)
                    acc[mt][nt] = __builtin_amdgcn_mfma_f32_16x16x32_bf16(
                        af[mt], bf[nt], acc[mt][nt], 0, 0, 0);
        }
        __syncthreads();
    }

    // epilogue: D row = quad*4 + reg, col = lane&15 (m89/m91 mapping)
    if constexpr (EPI == 0) {
        unsigned short* C = (unsigned short*)Cv;
#pragma unroll
        for (int mt = 0; mt < 4; ++mt)
#pragma unroll
            for (int nt = 0; nt < 4; ++nt)
#pragma unroll
                for (int r = 0; r < 4; ++r) {
                    const int row = m0 + wm * 64 + mt * 16 + quad * 4 + r;
                    const int col = n0 + wn * 64 + nt * 16 + lm;
                    C[(size_t)row * ldc + col] = f32_to_bf16(acc[mt][nt][r]);
                }
    } else if constexpr (EPI == 2) {
        float* C = (float*)Cv;
#pragma unroll
        for (int mt = 0; mt < 4; ++mt)
#pragma unroll
            for (int r = 0; r < 4; ++r) {
                const int row = m0 + wm * 64 + mt * 16 + quad * 4 + r;
                const float inv = 1.0f / rowsum[row];
#pragma unroll
                for (int nt = 0; nt < 4; ++nt) {
                    const int col = n0 + wn * 64 + nt * 16 + lm;
                    C[(size_t)row * ldc + col] = acc[mt][nt][r] * inv;
                }
            }
    }
}

// ---- Mp = WkTc . WqTc^T over K=3072 cat => (Hk+Lk)^T(Hq+Lq) - Lk^T Lq ----
__global__ __launch_bounds__(256, 4) void mp_kernel(
    const unsigned short* __restrict__ WkTc,
    const unsigned short* __restrict__ WqTc,
    unsigned short* __restrict__ Mp) {
    gemm_body<0>(WkTc, WqTc, Mp, 3072, 3072, 1024, 3072, 1.0f, nullptr,
                 blockIdx.x * BM, blockIdx.y * BN);
}

// ---- merged projections: z=0 q''=Xq@Mp^T ; z=1 vT=Wv@Xv^T (roles swapped) -
__global__ __launch_bounds__(256, 4) void proj_kernel(
    const unsigned short* __restrict__ Xq, const unsigned short* __restrict__ Mp,
    unsigned short* __restrict__ qb,
    const unsigned short* __restrict__ Wv, const unsigned short* __restrict__ Xv,
    unsigned short* __restrict__ vT) {
    const int z = blockIdx.z;
    const unsigned short* A = z == 0 ? Xq : Wv;
    const unsigned short* B = z == 0 ? Mp : Xv;
    unsigned short* C = z == 0 ? qb : vT;
    int m0, n0, ldc;
    if (z == 0) { m0 = blockIdx.x * BM; n0 = blockIdx.y * BN; ldc = 1024; }
    else        { m0 = blockIdx.y * BM; n0 = blockIdx.x * BN; ldc = 8192; }
    gemm_body<0>(A, B, C, 1024, 1024, ldc, 1024, 1.0f, nullptr, m0, n0);
}

__global__ __launch_bounds__(256, 4) void pv_kernel(
    const unsigned short* __restrict__ Sc, const unsigned short* __restrict__ vT,
    float* __restrict__ out, float* __restrict__ rowsum) {
    const long z = blockIdx.z;
    gemm_body<2>(Sc + z * 2048 * 2048, vT + z * 2048,
                 out + z * 2048 * 1024, 2048, 8192, 1024, 2048,
                 1.0f, rowsum + z * 2048,
                 blockIdx.x * BM, blockIdx.y * BN);
}

// ===========================================================================
// 256x256 8-phase body (scores only: 256 blocks = perfect 1/CU packing)
// ===========================================================================
template <int EPI>
__device__ __forceinline__ void gemm256_body(
    const unsigned short* __restrict__ A, const unsigned short* __restrict__ B,
    void* __restrict__ Cv, int lda, int ldb, int ldc, int K, float scale,
    float* __restrict__ rowsum, int m0, int n0) {
    __shared__ unsigned short As[2][256 * 64];
    __shared__ unsigned short Bs[2][256 * 64];

    const int tid   = threadIdx.x;
    const int wave  = tid >> 6;      // 0..7
    const int lane  = tid & 63;
    const int lm    = lane & 15;     // MFMA row-in-frag
    const int quad  = lane >> 4;     // 0..3
    const int wm    = wave >> 2;     // 0..1  (wave tile 2x4)
    const int wn    = wave & 3;      // 0..3
    const int srow8 = lane >> 3;
    const int gcol  = ((lane & 7) ^ srow8) * 8;  // pre-swizzled global col
    const int KT    = K >> 6;

#define STAGE_A(buf, half, kcol) do { \
        const int r0_ = (half) * 128 + wave * 8; \
        G2L(A + (size_t)(m0 + r0_ + srow8) * lda + (kcol) + gcol, \
            &As[buf][r0_ * 64]); \
        G2L(A + (size_t)(m0 + r0_ + 64 + srow8) * lda + (kcol) + gcol, \
            &As[buf][(r0_ + 64) * 64]); \
    } while (0)
#define STAGE_B(buf, half, kcol) do { \
        const int r0_ = (half) * 128 + wave * 8; \
        G2L(B + (size_t)(n0 + r0_ + srow8) * ldb + (kcol) + gcol, \
            &Bs[buf][r0_ * 64]); \
        G2L(B + (size_t)(n0 + r0_ + 64 + srow8) * ldb + (kcol) + gcol, \
            &Bs[buf][(r0_ + 64) * 64]); \
    } while (0)

    floatx4 acc[8][4];
#pragma unroll
    for (int i = 0; i < 8; ++i)
#pragma unroll
        for (int j = 0; j < 4; ++j) acc[i][j] = (floatx4)0.0f;

    // prologue: tile0 -> buf0, tile1 -> buf1 (8 loads each); vmcnt(8) => t0 landed
    STAGE_A(0, 0, 0); STAGE_A(0, 1, 0); STAGE_B(0, 0, 0); STAGE_B(0, 1, 0);
    if (KT > 1) {
        STAGE_A(1, 0, 64); STAGE_A(1, 1, 64);
        STAGE_B(1, 0, 64); STAGE_B(1, 1, 64);
        asm volatile("s_waitcnt vmcnt(8)" ::: "memory");
    } else {
        asm volatile("s_waitcnt vmcnt(0)" ::: "memory");
    }
    BAR();

    short8 aA[2][4];   // A half m0  (Q1, Q4)
    short8 aM[2][4];   // A half m1  (Q2, Q3)
    short8 bB[2][2];   // B half: n0 during Q1/Q2, overwritten with n1 at S3

    for (int kt = 0; kt < KT; ++kt) {
        const int b = kt & 1;
        const unsigned short* Ab = As[b];
        const unsigned short* Bb = Bs[b];

        // ---- S1: reads for Q1 (aA + bB=n0), then read-ahead aM (Q2) ----
#pragma unroll
        for (int s = 0; s < 2; ++s) {
            const int cs = ((s * 4 + quad) ^ (lm & 7)) * 8;
#pragma unroll
            for (int mt = 0; mt < 4; ++mt)
                aA[s][mt] = *(const short8*)&Ab[(wm * 128 + mt * 16 + lm) * 64 + cs];
#pragma unroll
            for (int nt = 0; nt < 2; ++nt)
                bB[s][nt] = *(const short8*)&Bb[(wn * 64 + nt * 16 + lm) * 64 + cs];
        }
#pragma unroll
        for (int s = 0; s < 2; ++s) {
            const int cs = ((s * 4 + quad) ^ (lm & 7)) * 8;
#pragma unroll
            for (int mt = 0; mt < 4; ++mt)
                aM[s][mt] = *(const short8*)&Ab[(wm * 128 + 64 + mt * 16 + lm) * 64 + cs];
        }
        BAR();
        // P1: MFMA Q1 (compiler waits counted lgkm; aM stays in flight)
        __builtin_amdgcn_s_setprio(1);
#pragma unroll
        for (int s = 0; s < 2; ++s)
#pragma unroll
            for (int mt = 0; mt < 4; ++mt)
#pragma unroll
                for (int nt = 0; nt < 2; ++nt)
                    acc[mt][nt] = __builtin_amdgcn_mfma_f32_16x16x32_bf16(
                        aA[s][mt], bB[s][nt], acc[mt][nt], 0, 0, 0);
        __builtin_amdgcn_s_setprio(0);
        BAR();

        // ---- S2: (no reads, no stages) ----
        BAR();
        // P2: MFMA Q2
        __builtin_amdgcn_s_setprio(1);
#pragma unroll
        for (int s = 0; s < 2; ++s)
#pragma unroll
            for (int mt = 0; mt < 4; ++mt)
#pragma unroll
                for (int nt = 0; nt < 2; ++nt)
                    acc[4 + mt][nt] = __builtin_amdgcn_mfma_f32_16x16x32_bf16(
                        aM[s][mt], bB[s][nt], acc[4 + mt][nt], 0, 0, 0);
        __builtin_amdgcn_s_setprio(0);
        BAR();

        // ---- S3: read bB=n1 (A-reads all done by P2-close); stage A(t+2) ----
#pragma unroll
        for (int s = 0; s < 2; ++s) {
            const int cs = ((s * 4 + quad) ^ (lm & 7)) * 8;
#pragma unroll
            for (int nt = 0; nt < 2; ++nt)
                bB[s][nt] = *(const short8*)&Bb[(wn * 64 + 32 + nt * 16 + lm) * 64 + cs];
        }
        if (kt + 2 < KT) { STAGE_A(b, 0, (kt + 2) * 64); STAGE_A(b, 1, (kt + 2) * 64); }
        BAR();
        // P3: MFMA Q3
        __builtin_amdgcn_s_setprio(1);
#pragma unroll
        for (int s = 0; s < 2; ++s)
#pragma unroll
            for (int mt = 0; mt < 4; ++mt)
#pragma unroll
                for (int nt = 0; nt < 2; ++nt)
                    acc[4 + mt][2 + nt] = __builtin_amdgcn_mfma_f32_16x16x32_bf16(
                        aM[s][mt], bB[s][nt], acc[4 + mt][2 + nt], 0, 0, 0);
        __builtin_amdgcn_s_setprio(0);
        BAR();

        // ---- S4: stage B(t+2) (B-reads all done by P3-close) ----
        if (kt + 2 < KT) { STAGE_B(b, 0, (kt + 2) * 64); STAGE_B(b, 1, (kt + 2) * 64); }
        BAR();
        // P4: MFMA Q4; then counted vmcnt => tile t+1 landed; publish barrier
        __builtin_amdgcn_s_setprio(1);
#pragma unroll
        for (int s = 0; s < 2; ++s)
#pragma unroll
            for (int mt = 0; mt < 4; ++mt)
#pragma unroll
                for (int nt = 0; nt < 2; ++nt)
                    acc[mt][2 + nt] = __builtin_amdgcn_mfma_f32_16x16x32_bf16(
                        aA[s][mt], bB[s][nt], acc[mt][2 + nt], 0, 0, 0);
        __builtin_amdgcn_s_setprio(0);
        if (kt + 2 < KT) {
            asm volatile("s_waitcnt vmcnt(8)" ::: "memory");
        } else if (kt + 1 < KT) {
            asm volatile("s_waitcnt vmcnt(0)" ::: "memory");
        }
        BAR();
    }
#undef STAGE_A
#undef STAGE_B

    // epilogue: D row = quad*4 + reg, col = lane&15 (m89/m91 mapping)
    if constexpr (EPI == 1) {
        unsigned short* C = (unsigned short*)Cv;
        float psum[8][4];
#pragma unroll
        for (int f = 0; f < 8; ++f)
#pragma unroll
            for (int r = 0; r < 4; ++r) psum[f][r] = 0.0f;
#pragma unroll
        for (int f = 0; f < 8; ++f)
#pragma unroll
            for (int g = 0; g < 4; ++g)
#pragma unroll
                for (int r = 0; r < 4; ++r) {
                    const int row = m0 + wm * 128 + f * 16 + quad * 4 + r;
                    const int col = n0 + wn * 64 + g * 16 + lm;
                    const float p = __expf(acc[f][g][r] * scale);
                    psum[f][r] += p;
                    C[(size_t)row * ldc + col] = f32_to_bf16(p);
                }
#pragma unroll
        for (int off = 1; off <= 8; off <<= 1)
#pragma unroll
            for (int f = 0; f < 8; ++f)
#pragma unroll
                for (int r = 0; r < 4; ++r)
                    psum[f][r] += __shfl_xor(psum[f][r], off);
        if (lm == 0) {
#pragma unroll
            for (int f = 0; f < 8; ++f)
#pragma unroll
                for (int r = 0; r < 4; ++r)
                    atomicAdd(&rowsum[m0 + wm * 128 + f * 16 + quad * 4 + r],
                              psum[f][r]);
        }
    }
}

__global__ __launch_bounds__(512, 2) void scores256_kernel(
    const unsigned short* __restrict__ qb, const unsigned short* __restrict__ Xk,
    unsigned short* __restrict__ Sc, float* __restrict__ rowsum) {
    const long z = blockIdx.z;
    gemm256_body<1>(qb + z * 2048 * 1024, Xk + z * 2048 * 1024,
                    Sc + z * 2048 * 2048, 1024, 1024, 2048, 1024,
                    1.0f / 32.0f, rowsum + z * 2048,
                    blockIdx.x * 256, blockIdx.y * 256);
}

// ---------------------------------------------------------------------------
extern "C" void kernel_launch(void* const* d_in, const int* in_sizes, int n_in,
                              void* d_out, int out_size, void* d_ws, size_t ws_size,
                              hipStream_t stream) {
    const float* q_in = (const float*)d_in[0];
    const float* k_in = (const float*)d_in[1];
    const float* v_in = (const float*)d_in[2];
    const float* Qw_f = (const float*)d_in[3];
    const float* Kw_f = (const float*)d_in[4];
    const float* Vw_f = (const float*)d_in[5];
    float* out = (float*)d_out;

    const int Bb = 4, S = 2048, E = 1024;
    const size_t TOK = (size_t)Bb * S;       // 8192
    const size_t NTE = TOK * E;              // 8,388,608
    const size_t NW  = (size_t)E * E;        // 1,048,576
    const size_t NWC = (size_t)E * 3072;     // 3,145,728 (split-cat weights)

    unsigned short* ws = (unsigned short*)d_ws;
    unsigned short* Xq = ws;            // [8192,1024]
    unsigned short* Xk = Xq + NTE;
    unsigned short* Xv = Xk + NTE;
    unsigned short* Wv = Xv + NTE;      // [1024,1024]
    unsigned short* WkTc = Wv + NW;     // [1024 t][3072] = [Hk|Lk|Hk]
    unsigned short* WqTc = WkTc + NWC;  // [1024 k][3072] = [Hq|Hq|Lq]
    unsigned short* Mp = WqTc + NWC;    // [1024 t][1024 k]
    unsigned short* qb = Mp + NW;       // [8192,1024]  q'' = Xq @ Mp^T
    unsigned short* vT = qb + NTE;      // [1024 e][8192 tok]
    unsigned short* Sc = vT + NTE;      // [4][2048][2048] exp-scores
    float* rowsum = (float*)(Sc + (size_t)Bb * S * S);  // [4][2048]

    // 1) converts (3X + Wv) + rowsum zero + W transposes (H/L split-cat)
    cvt_all<<<CVT_BLOCKS + TR_BLOCKS, 256, 0, stream>>>(
        q_in, k_in, v_in, Qw_f, Kw_f, Vw_f,
        Xq, Xk, Xv, Wv, WkTc, WqTc, rowsum);

    // 2) Mp = Wk^T Wq (fp32-accurate via split-precision MFMA, 64 blocks)
    mp_kernel<<<dim3(8, 8), 256, 0, stream>>>(WkTc, WqTc, Mp);

    // 3) q'' and vT, one dispatch (1024 blocks = perfect 4/CU packing)
    proj_kernel<<<dim3(TOK / BM, E / BN, 2), 256, 0, stream>>>(
        Xq, Mp, qb, Wv, Xv, vT);

    // 4) P = exp(q'' Xk^T / 32) + fp32 rowsums (256 blocks, perfect packing)
    scores256_kernel<<<dim3(S / 256, S / 256, 4), 512, 0, stream>>>(
        qb, Xk, Sc, rowsum);

    // 5) out = (P @ v) / rowsum  (128^2 body, 512 blocks, 4/CU)
    pv_kernel<<<dim3(S / BM, E / BN, 4), 256, 0, stream>>>(
        Sc, vT, out, rowsum);
}

// Round 6
// 306.224 us; speedup vs baseline: 1.3094x; 1.0787x over previous
//
#include <hip/hip_runtime.h>
#include <stdint.h>

// ---------------------------------------------------------------------------
// SelfAttention: B=4, S=2048, E=1024 (single head)
// Algebra (validated R12/R13): scores = Xq·Wq^T·Wk·Xk^T = NT(q'', Xk) with
//   Mp[t,k] = sum_o Wk[o,t]*Wq[o,k]  (1024x1024)   -- k-projection DELETED
//   q''     = NT(Xq, Mp)
// R14: Mp blocks MERGED into the cvt dispatch (self-contained: read only raw
// fp32 weights -> no inter-block dependency). 256 MFMA side-blocks (64x64
// tiles) at grid front; each chunk: coalesced fp32 load -> transposed fp32
// LDS tile (conflict-free) -> in-register H/L bf16 frags -> 3-pass MFMA
// (HH+LH+HL ~ fp32-accurate). Their ~17us latency chains hide under cvt's
// ~28us BW-bound streaming. R13's separate mp_kernel (52us: 48-step
// dependent chain, 1 block/CU, no TLP) is deleted; back to 4 dispatches.
//   vT = Wv @ Xv^T;  P = exp(q'' Xk^T / 32);  out = P v / rowsum
// ---------------------------------------------------------------------------

typedef __attribute__((ext_vector_type(8))) short short8;       // 8 x bf16 frag
typedef __attribute__((ext_vector_type(4))) float floatx4;      // MFMA acc
typedef __attribute__((ext_vector_type(4))) unsigned short u16x4;
typedef __attribute__((ext_vector_type(4))) float f32x4v;

__device__ __forceinline__ unsigned short f32_to_bf16(float f) {
    union { float f; unsigned u; } c; c.f = f;
    unsigned u = c.u;
    return (unsigned short)((u + 0x7fffu + ((u >> 16) & 1u)) >> 16);  // RNE
}

#define G2L(g, l) __builtin_amdgcn_global_load_lds( \
    (__attribute__((address_space(1))) void*)(void*)(g), \
    (__attribute__((address_space(3))) void*)(l), 16, 0, 0)

#define BAR() __builtin_amdgcn_s_barrier()

// ---- cvt dispatch: 256 Mp MFMA blocks + streaming converts + rowsum zero --
#define MP_BLOCKS 256
#define CVT_BLOCKS 25608   // (3*2097152 + 262144 + 2048) / 256

__global__ __launch_bounds__(256) void cvt_all(
    const float* __restrict__ q, const float* __restrict__ k,
    const float* __restrict__ v, const float* __restrict__ wq,
    const float* __restrict__ wk, const float* __restrict__ wv,
    unsigned short* __restrict__ Xq, unsigned short* __restrict__ Xk,
    unsigned short* __restrict__ Xv, unsigned short* __restrict__ Wv,
    unsigned short* __restrict__ Mp, float* __restrict__ rowsum) {
    __shared__ float TtA[64][33];   // transposed fp32 chunk: [t][o], pad->2-way
    __shared__ float TtB[64][33];   // [k][o]

    if (blockIdx.x < MP_BLOCKS) {
        // ---- Mp[t,k] = sum_o Wk[o,t]*Wq[o,k], 64x64 tile, split-precision --
        const int id   = blockIdx.x;
        const int t0   = (id >> 4) * 64;
        const int k0   = (id & 15) * 64;
        const int tid  = threadIdx.x;
        const int lane = tid & 63;
        const int wave = tid >> 6;
        const int wm   = wave >> 1;      // 2x2 waves of 32x32
        const int wn   = wave & 1;
        const int lm   = lane & 15;
        const int quad = lane >> 4;
        const int r    = tid >> 3;       // o-local row 0..31
        const int c8   = (tid & 7) * 8;  // t/k-local col base

        floatx4 acc[2][2];
#pragma unroll
        for (int i = 0; i < 2; ++i)
#pragma unroll
            for (int j = 0; j < 2; ++j) acc[i][j] = (floatx4)0.0f;

        for (int o0 = 0; o0 < 1024; o0 += 32) {
            const float* pa = &wk[(size_t)(o0 + r) * 1024 + t0 + c8];
            const float* pb = &wq[(size_t)(o0 + r) * 1024 + k0 + c8];
            const f32x4v a0 = *(const f32x4v*)pa;
            const f32x4v a1 = *(const f32x4v*)(pa + 4);
            const f32x4v b0 = *(const f32x4v*)pb;
            const f32x4v b1 = *(const f32x4v*)(pb + 4);
            __syncthreads();   // previous chunk's frag reads done
#pragma unroll
            for (int j = 0; j < 4; ++j) {
                TtA[c8 + j][r]     = a0[j];
                TtA[c8 + 4 + j][r] = a1[j];
                TtB[c8 + j][r]     = b0[j];
                TtB[c8 + 4 + j][r] = b1[j];
            }
            __syncthreads();

            short8 aH[2], aL[2], bH[2], bL[2];
#pragma unroll
            for (int mt = 0; mt < 2; ++mt) {
                const int rowA = wm * 32 + mt * 16 + lm;
                const int rowB = wn * 32 + mt * 16 + lm;
#pragma unroll
                for (int e = 0; e < 8; ++e) {
                    const float fa = TtA[rowA][quad * 8 + e];
                    const unsigned short ha = f32_to_bf16(fa);
                    union { unsigned u; float f; } ca; ca.u = (unsigned)ha << 16;
                    aH[mt][e] = (short)ha;
                    aL[mt][e] = (short)f32_to_bf16(fa - ca.f);
                    const float fb = TtB[rowB][quad * 8 + e];
                    const unsigned short hb = f32_to_bf16(fb);
                    union { unsigned u; float f; } cb; cb.u = (unsigned)hb << 16;
                    bH[mt][e] = (short)hb;
                    bL[mt][e] = (short)f32_to_bf16(fb - cb.f);
                }
            }
#pragma unroll
            for (int mt = 0; mt < 2; ++mt)
#pragma unroll
                for (int nt = 0; nt < 2; ++nt) {
                    acc[mt][nt] = __builtin_amdgcn_mfma_f32_16x16x32_bf16(
                        aH[mt], bH[nt], acc[mt][nt], 0, 0, 0);
                    acc[mt][nt] = __builtin_amdgcn_mfma_f32_16x16x32_bf16(
                        aL[mt], bH[nt], acc[mt][nt], 0, 0, 0);
                    acc[mt][nt] = __builtin_amdgcn_mfma_f32_16x16x32_bf16(
                        aH[mt], bL[nt], acc[mt][nt], 0, 0, 0);
                }
        }
        // epilogue: D row = quad*4 + rr, col = lm (m89/m91 mapping)
#pragma unroll
        for (int mt = 0; mt < 2; ++mt)
#pragma unroll
            for (int nt = 0; nt < 2; ++nt)
#pragma unroll
                for (int rr = 0; rr < 4; ++rr) {
                    const int row = t0 + wm * 32 + mt * 16 + quad * 4 + rr;
                    const int col = k0 + wn * 32 + nt * 16 + lm;
                    Mp[(size_t)row * 1024 + col] = f32_to_bf16(acc[mt][nt][rr]);
                }
        return;
    }

    // ---- streaming converts (3X + Wv) + rowsum zero ----
    const long NTE4 = 2097152;  // 8192*1024/4
    const long NW4  = 262144;   // 1024*1024/4
    long i = (long)(blockIdx.x - MP_BLOCKS) * 256 + threadIdx.x;
    const float* src;
    unsigned short* dst;
    long j;
    if (i < 3 * NTE4) {
        int a = (int)(i / NTE4); j = i - (long)a * NTE4;
        src = a == 0 ? q : a == 1 ? k : v;
        dst = a == 0 ? Xq : a == 1 ? Xk : Xv;
    } else {
        i -= 3 * NTE4;
        if (i < NW4) {
            src = wv; dst = Wv; j = i;
        } else {
            i -= NW4;           // 2048 groups -> rowsum[0..8191] = 0
            if (i < 2048) ((f32x4v*)rowsum)[i] = (f32x4v)0.0f;
            return;
        }
    }
    f32x4v f = ((const f32x4v*)src)[j];
    u16x4 o;
#pragma unroll
    for (int t = 0; t < 4; ++t) o[t] = f32_to_bf16(f[t]);
    ((u16x4*)dst)[j] = o;
}

// ===========================================================================
// 128x128 body (proj + pv: proven 942 TF structure)
// ===========================================================================
#define BM 128
#define BN 128
#define BK 64

// EPI: 0 = store bf16; 2 = store fp32 x / rowsum[row]
template <int EPI>
__device__ __forceinline__ void gemm_body(
    const unsigned short* __restrict__ A, const unsigned short* __restrict__ B,
    void* __restrict__ Cv, int lda, int ldb, int ldc, int K, float scale,
    float* __restrict__ rowsum, int m0, int n0) {
    __shared__ unsigned short As[BM * BK];
    __shared__ unsigned short Bs[BN * BK];

    const int tid  = threadIdx.x;
    const int wave = tid >> 6;
    const int lane = tid & 63;
    const int lm   = lane & 15;
    const int quad = lane >> 4;
    const int wm   = wave >> 1;
    const int wn   = wave & 1;

    const int srow8 = lane >> 3;
    const int gcol  = ((lane & 7) ^ srow8) * 8;

    floatx4 acc[4][4];
#pragma unroll
    for (int i = 0; i < 4; ++i)
#pragma unroll
        for (int j = 0; j < 4; ++j) acc[i][j] = (floatx4)0.0f;

    for (int k0 = 0; k0 < K; k0 += BK) {
#pragma unroll
        for (int i = 0; i < 4; ++i) {
            const int rbase = wave * 32 + i * 8;
            G2L(A + (size_t)(m0 + rbase + srow8) * lda + k0 + gcol,
                &As[rbase * BK]);
            G2L(B + (size_t)(n0 + rbase + srow8) * ldb + k0 + gcol,
                &Bs[rbase * BK]);
        }
        __syncthreads();

#pragma unroll
        for (int s = 0; s < 2; ++s) {
            short8 af[4], bf[4];
#pragma unroll
            for (int t = 0; t < 4; ++t) {
                const int cs = ((s * 4 + quad) ^ (lm & 7)) * 8;
                af[t] = *(const short8*)&As[(wm * 64 + t * 16 + lm) * BK + cs];
                bf[t] = *(const short8*)&Bs[(wn * 64 + t * 16 + lm) * BK + cs];
            }
#pragma unroll
            for (int mt = 0; mt < 4; ++mt)
#pragma unroll
                for (int nt = 0; nt < 4; ++nt)
                    acc[mt][nt] = __builtin_amdgcn_mfma_f32_16x16x32_bf16(
                        af[mt], bf[nt], acc[mt][nt], 0, 0, 0);
        }
        __syncthreads();
    }

    // epilogue: D row = quad*4 + reg, col = lane&15 (m89/m91 mapping)
    if constexpr (EPI == 0) {
        unsigned short* C = (unsigned short*)Cv;
#pragma unroll
        for (int mt = 0; mt < 4; ++mt)
#pragma unroll
            for (int nt = 0; nt < 4; ++nt)
#pragma unroll
                for (int r = 0; r < 4; ++r) {
                    const int row = m0 + wm * 64 + mt * 16 + quad * 4 + r;
                    const int col = n0 + wn * 64 + nt * 16 + lm;
                    C[(size_t)row * ldc + col] = f32_to_bf16(acc[mt][nt][r]);
                }
    } else if constexpr (EPI == 2) {
        float* C = (float*)Cv;
#pragma unroll
        for (int mt = 0; mt < 4; ++mt)
#pragma unroll
            for (int r = 0; r < 4; ++r) {
                const int row = m0 + wm * 64 + mt * 16 + quad * 4 + r;
                const float inv = 1.0f / rowsum[row];
#pragma unroll
                for (int nt = 0; nt < 4; ++nt) {
                    const int col = n0 + wn * 64 + nt * 16 + lm;
                    C[(size_t)row * ldc + col] = acc[mt][nt][r] * inv;
                }
            }
    }
}

// ---- merged projections: z=0 q''=Xq@Mp^T ; z=1 vT=Wv@Xv^T (roles swapped) -
__global__ __launch_bounds__(256, 4) void proj_kernel(
    const unsigned short* __restrict__ Xq, const unsigned short* __restrict__ Mp,
    unsigned short* __restrict__ qb,
    const unsigned short* __restrict__ Wv, const unsigned short* __restrict__ Xv,
    unsigned short* __restrict__ vT) {
    const int z = blockIdx.z;
    const unsigned short* A = z == 0 ? Xq : Wv;
    const unsigned short* B = z == 0 ? Mp : Xv;
    unsigned short* C = z == 0 ? qb : vT;
    int m0, n0, ldc;
    if (z == 0) { m0 = blockIdx.x * BM; n0 = blockIdx.y * BN; ldc = 1024; }
    else        { m0 = blockIdx.y * BM; n0 = blockIdx.x * BN; ldc = 8192; }
    gemm_body<0>(A, B, C, 1024, 1024, ldc, 1024, 1.0f, nullptr, m0, n0);
}

__global__ __launch_bounds__(256, 4) void pv_kernel(
    const unsigned short* __restrict__ Sc, const unsigned short* __restrict__ vT,
    float* __restrict__ out, float* __restrict__ rowsum) {
    const long z = blockIdx.z;
    gemm_body<2>(Sc + z * 2048 * 2048, vT + z * 2048,
                 out + z * 2048 * 1024, 2048, 8192, 1024, 2048,
                 1.0f, rowsum + z * 2048,
                 blockIdx.x * BM, blockIdx.y * BN);
}

// ===========================================================================
// 256x256 8-phase body (scores only: 256 blocks = perfect 1/CU packing)
// ===========================================================================
template <int EPI>
__device__ __forceinline__ void gemm256_body(
    const unsigned short* __restrict__ A, const unsigned short* __restrict__ B,
    void* __restrict__ Cv, int lda, int ldb, int ldc, int K, float scale,
    float* __restrict__ rowsum, int m0, int n0) {
    __shared__ unsigned short As[2][256 * 64];
    __shared__ unsigned short Bs[2][256 * 64];

    const int tid   = threadIdx.x;
    const int wave  = tid >> 6;      // 0..7
    const int lane  = tid & 63;
    const int lm    = lane & 15;     // MFMA row-in-frag
    const int quad  = lane >> 4;     // 0..3
    const int wm    = wave >> 2;     // 0..1  (wave tile 2x4)
    const int wn    = wave & 3;      // 0..3
    const int srow8 = lane >> 3;
    const int gcol  = ((lane & 7) ^ srow8) * 8;  // pre-swizzled global col
    const int KT    = K >> 6;

#define STAGE_A(buf, half, kcol) do { \
        const int r0_ = (half) * 128 + wave * 8; \
        G2L(A + (size_t)(m0 + r0_ + srow8) * lda + (kcol) + gcol, \
            &As[buf][r0_ * 64]); \
        G2L(A + (size_t)(m0 + r0_ + 64 + srow8) * lda + (kcol) + gcol, \
            &As[buf][(r0_ + 64) * 64]); \
    } while (0)
#define STAGE_B(buf, half, kcol) do { \
        const int r0_ = (half) * 128 + wave * 8; \
        G2L(B + (size_t)(n0 + r0_ + srow8) * ldb + (kcol) + gcol, \
            &Bs[buf][r0_ * 64]); \
        G2L(B + (size_t)(n0 + r0_ + 64 + srow8) * ldb + (kcol) + gcol, \
            &Bs[buf][(r0_ + 64) * 64]); \
    } while (0)

    floatx4 acc[8][4];
#pragma unroll
    for (int i = 0; i < 8; ++i)
#pragma unroll
        for (int j = 0; j < 4; ++j) acc[i][j] = (floatx4)0.0f;

    // prologue: tile0 -> buf0, tile1 -> buf1 (8 loads each); vmcnt(8) => t0 landed
    STAGE_A(0, 0, 0); STAGE_A(0, 1, 0); STAGE_B(0, 0, 0); STAGE_B(0, 1, 0);
    if (KT > 1) {
        STAGE_A(1, 0, 64); STAGE_A(1, 1, 64);
        STAGE_B(1, 0, 64); STAGE_B(1, 1, 64);
        asm volatile("s_waitcnt vmcnt(8)" ::: "memory");
    } else {
        asm volatile("s_waitcnt vmcnt(0)" ::: "memory");
    }
    BAR();

    short8 aA[2][4];   // A half m0  (Q1, Q4)
    short8 aM[2][4];   // A half m1  (Q2, Q3)
    short8 bB[2][2];   // B half: n0 during Q1/Q2, overwritten with n1 at S3

    for (int kt = 0; kt < KT; ++kt) {
        const int b = kt & 1;
        const unsigned short* Ab = As[b];
        const unsigned short* Bb = Bs[b];

        // ---- S1: reads for Q1 (aA + bB=n0), then read-ahead aM (Q2) ----
#pragma unroll
        for (int s = 0; s < 2; ++s) {
            const int cs = ((s * 4 + quad) ^ (lm & 7)) * 8;
#pragma unroll
            for (int mt = 0; mt < 4; ++mt)
                aA[s][mt] = *(const short8*)&Ab[(wm * 128 + mt * 16 + lm) * 64 + cs];
#pragma unroll
            for (int nt = 0; nt < 2; ++nt)
                bB[s][nt] = *(const short8*)&Bb[(wn * 64 + nt * 16 + lm) * 64 + cs];
        }
#pragma unroll
        for (int s = 0; s < 2; ++s) {
            const int cs = ((s * 4 + quad) ^ (lm & 7)) * 8;
#pragma unroll
            for (int mt = 0; mt < 4; ++mt)
                aM[s][mt] = *(const short8*)&Ab[(wm * 128 + 64 + mt * 16 + lm) * 64 + cs];
        }
        BAR();
        // P1: MFMA Q1 (compiler waits counted lgkm; aM stays in flight)
        __builtin_amdgcn_s_setprio(1);
#pragma unroll
        for (int s = 0; s < 2; ++s)
#pragma unroll
            for (int mt = 0; mt < 4; ++mt)
#pragma unroll
                for (int nt = 0; nt < 2; ++nt)
                    acc[mt][nt] = __builtin_amdgcn_mfma_f32_16x16x32_bf16(
                        aA[s][mt], bB[s][nt], acc[mt][nt], 0, 0, 0);
        __builtin_amdgcn_s_setprio(0);
        BAR();

        // ---- S2: (no reads, no stages) ----
        BAR();
        // P2: MFMA Q2
        __builtin_amdgcn_s_setprio(1);
#pragma unroll
        for (int s = 0; s < 2; ++s)
#pragma unroll
            for (int mt = 0; mt < 4; ++mt)
#pragma unroll
                for (int nt = 0; nt < 2; ++nt)
                    acc[4 + mt][nt] = __builtin_amdgcn_mfma_f32_16x16x32_bf16(
                        aM[s][mt], bB[s][nt], acc[4 + mt][nt], 0, 0, 0);
        __builtin_amdgcn_s_setprio(0);
        BAR();

        // ---- S3: read bB=n1 (A-reads all done by P2-close); stage A(t+2) ----
#pragma unroll
        for (int s = 0; s < 2; ++s) {
            const int cs = ((s * 4 + quad) ^ (lm & 7)) * 8;
#pragma unroll
            for (int nt = 0; nt < 2; ++nt)
                bB[s][nt] = *(const short8*)&Bb[(wn * 64 + 32 + nt * 16 + lm) * 64 + cs];
        }
        if (kt + 2 < KT) { STAGE_A(b, 0, (kt + 2) * 64); STAGE_A(b, 1, (kt + 2) * 64); }
        BAR();
        // P3: MFMA Q3
        __builtin_amdgcn_s_setprio(1);
#pragma unroll
        for (int s = 0; s < 2; ++s)
#pragma unroll
            for (int mt = 0; mt < 4; ++mt)
#pragma unroll
                for (int nt = 0; nt < 2; ++nt)
                    acc[4 + mt][2 + nt] = __builtin_amdgcn_mfma_f32_16x16x32_bf16(
                        aM[s][mt], bB[s][nt], acc[4 + mt][2 + nt], 0, 0, 0);
        __builtin_amdgcn_s_setprio(0);
        BAR();

        // ---- S4: stage B(t+2) (B-reads all done by P3-close) ----
        if (kt + 2 < KT) { STAGE_B(b, 0, (kt + 2) * 64); STAGE_B(b, 1, (kt + 2) * 64); }
        BAR();
        // P4: MFMA Q4; then counted vmcnt => tile t+1 landed; publish barrier
        __builtin_amdgcn_s_setprio(1);
#pragma unroll
        for (int s = 0; s < 2; ++s)
#pragma unroll
            for (int mt = 0; mt < 4; ++mt)
#pragma unroll
                for (int nt = 0; nt < 2; ++nt)
                    acc[mt][2 + nt] = __builtin_amdgcn_mfma_f32_16x16x32_bf16(
                        aA[s][mt], bB[s][nt], acc[mt][2 + nt], 0, 0, 0);
        __builtin_amdgcn_s_setprio(0);
        if (kt + 2 < KT) {
            asm volatile("s_waitcnt vmcnt(8)" ::: "memory");
        } else if (kt + 1 < KT) {
            asm volatile("s_waitcnt vmcnt(0)" ::: "memory");
        }
        BAR();
    }
#undef STAGE_A
#undef STAGE_B

    // epilogue: D row = quad*4 + reg, col = lane&15 (m89/m91 mapping)
    if constexpr (EPI == 1) {
        unsigned short* C = (unsigned short*)Cv;
        float psum[8][4];
#pragma unroll
        for (int f = 0; f < 8; ++f)
#pragma unroll
            for (int r = 0; r < 4; ++r) psum[f][r] = 0.0f;
#pragma unroll
        for (int f = 0; f < 8; ++f)
#pragma unroll
            for (int g = 0; g < 4; ++g)
#pragma unroll
                for (int r = 0; r < 4; ++r) {
                    const int row = m0 + wm * 128 + f * 16 + quad * 4 + r;
                    const int col = n0 + wn * 64 + g * 16 + lm;
                    const float p = __expf(acc[f][g][r] * scale);
                    psum[f][r] += p;
                    C[(size_t)row * ldc + col] = f32_to_bf16(p);
                }
#pragma unroll
        for (int off = 1; off <= 8; off <<= 1)
#pragma unroll
            for (int f = 0; f < 8; ++f)
#pragma unroll
                for (int r = 0; r < 4; ++r)
                    psum[f][r] += __shfl_xor(psum[f][r], off);
        if (lm == 0) {
#pragma unroll
            for (int f = 0; f < 8; ++f)
#pragma unroll
                for (int r = 0; r < 4; ++r)
                    atomicAdd(&rowsum[m0 + wm * 128 + f * 16 + quad * 4 + r],
                              psum[f][r]);
        }
    }
}

__global__ __launch_bounds__(512, 2) void scores256_kernel(
    const unsigned short* __restrict__ qb, const unsigned short* __restrict__ Xk,
    unsigned short* __restrict__ Sc, float* __restrict__ rowsum) {
    const long z = blockIdx.z;
    gemm256_body<1>(qb + z * 2048 * 1024, Xk + z * 2048 * 1024,
                    Sc + z * 2048 * 2048, 1024, 1024, 2048, 1024,
                    1.0f / 32.0f, rowsum + z * 2048,
                    blockIdx.x * 256, blockIdx.y * 256);
}

// ---------------------------------------------------------------------------
extern "C" void kernel_launch(void* const* d_in, const int* in_sizes, int n_in,
                              void* d_out, int out_size, void* d_ws, size_t ws_size,
                              hipStream_t stream) {
    const float* q_in = (const float*)d_in[0];
    const float* k_in = (const float*)d_in[1];
    const float* v_in = (const float*)d_in[2];
    const float* Qw_f = (const float*)d_in[3];
    const float* Kw_f = (const float*)d_in[4];
    const float* Vw_f = (const float*)d_in[5];
    float* out = (float*)d_out;

    const int Bb = 4, S = 2048, E = 1024;
    const size_t TOK = (size_t)Bb * S;       // 8192
    const size_t NTE = TOK * E;              // 8,388,608
    const size_t NW  = (size_t)E * E;        // 1,048,576

    unsigned short* ws = (unsigned short*)d_ws;
    unsigned short* Xq = ws;            // [8192,1024]
    unsigned short* Xk = Xq + NTE;
    unsigned short* Xv = Xk + NTE;
    unsigned short* Wv = Xv + NTE;      // [1024,1024]
    unsigned short* Mp = Wv + NW;       // [1024 t][1024 k] = Wk^T Wq (as NT rows)
    unsigned short* qb = Mp + NW;       // [8192,1024]  q'' = Xq @ Mp^T
    unsigned short* vT = qb + NTE;      // [1024 e][8192 tok]
    unsigned short* Sc = vT + NTE;      // [4][2048][2048] exp-scores
    float* rowsum = (float*)(Sc + (size_t)Bb * S * S);  // [4][2048]

    // 1) Mp side-blocks (MFMA, self-contained) + converts + rowsum zero
    cvt_all<<<MP_BLOCKS + CVT_BLOCKS, 256, 0, stream>>>(
        q_in, k_in, v_in, Qw_f, Kw_f, Vw_f,
        Xq, Xk, Xv, Wv, Mp, rowsum);

    // 2) q'' and vT, one dispatch (1024 blocks = perfect 4/CU packing)
    proj_kernel<<<dim3(TOK / BM, E / BN, 2), 256, 0, stream>>>(
        Xq, Mp, qb, Wv, Xv, vT);

    // 3) P = exp(q'' Xk^T / 32) + fp32 rowsums (256 blocks, perfect packing)
    scores256_kernel<<<dim3(S / 256, S / 256, 4), 512, 0, stream>>>(
        qb, Xk, Sc, rowsum);

    // 4) out = (P @ v) / rowsum  (128^2 body, 512 blocks, 4/CU)
    pv_kernel<<<dim3(S / BM, E / BN, 4), 256, 0, stream>>>(
        Sc, vT, out, rowsum);
}

// Round 7
// 297.988 us; speedup vs baseline: 1.3456x; 1.0276x over previous
//
#include <hip/hip_runtime.h>
#include <stdint.h>

// ---------------------------------------------------------------------------
// SelfAttention: B=4, S=2048, E=1024 (single head)
// Algebra (validated R12/R13/R14): scores = Xq·Wq^T·Wk·Xk^T = NT(q'', Xk):
//   Mp[t,k] = sum_o Wk[o,t]*Wq[o,k]  (1024x1024)   -- k-projection DELETED
//   q''     = NT(Xq, Mp)
// R15: Mp in a DEDICATED pipelined kernel (contention-free). Three failed
// placements taught: fp32-VALU fused = 130us (no fp32 MFMA); 64-block
// chain kernel = 52us (48 serial latency steps); front-fused MFMA blocks =
// +45us (chain x streaming contention). Now: 256 blocks (1/CU exclusive),
// 16 iters of 64-o chunks, register-staged prefetch (chunk t+1 loads issue
// after publish-barrier, latency hides under chunk t convert+MFMA),
// split-precision HH+LH+HL MFMA (validated: absmax bit-identical).
//   vT = Wv @ Xv^T;  P = exp(q'' Xk^T / 32);  out = P v / rowsum
// ---------------------------------------------------------------------------

typedef __attribute__((ext_vector_type(8))) short short8;       // 8 x bf16 frag
typedef __attribute__((ext_vector_type(4))) float floatx4;      // MFMA acc
typedef __attribute__((ext_vector_type(4))) unsigned short u16x4;
typedef __attribute__((ext_vector_type(4))) float f32x4v;

__device__ __forceinline__ unsigned short f32_to_bf16(float f) {
    union { float f; unsigned u; } c; c.f = f;
    unsigned u = c.u;
    return (unsigned short)((u + 0x7fffu + ((u >> 16) & 1u)) >> 16);  // RNE
}

#define G2L(g, l) __builtin_amdgcn_global_load_lds( \
    (__attribute__((address_space(1))) void*)(void*)(g), \
    (__attribute__((address_space(3))) void*)(l), 16, 0, 0)

#define BAR() __builtin_amdgcn_s_barrier()

// ===========================================================================
// mp_kernel: Mp[t,k] = sum_o Wk[o,t]*Wq[o,k], 64x64 tile/block, 256 blocks.
// Per iter (64 o-rows): publish reg-staged fp32 chunk into transposed LDS
// (pad 65 -> 2-way max, free), prefetch next chunk into regs (latency hides
// under frag-convert + 24 MFMA). Split-precision: H=bf16(w), L=bf16(w-H);
// acc += Hk^T Hq + Lk^T Hq + Hk^T Lq  (~fp32-accurate, one final rounding).
// Fragment/epilogue index math identical to R14's validated block.
// ===========================================================================
__global__ __launch_bounds__(256) void mp_kernel(
    const float* __restrict__ wk, const float* __restrict__ wq,
    unsigned short* __restrict__ Mp) {
    __shared__ float TtA[64][65];   // [t-local][o-local]
    __shared__ float TtB[64][65];   // [k-local][o-local]

    const int t0   = ((int)blockIdx.x >> 4) * 64;
    const int k0   = ((int)blockIdx.x & 15) * 64;
    const int tid  = threadIdx.x;
    const int lane = tid & 63;
    const int wave = tid >> 6;
    const int wm   = wave >> 1;      // 2x2 waves of 32x32
    const int wn   = wave & 1;
    const int lm   = lane & 15;
    const int quad = lane >> 4;
    const int r    = tid >> 2;       // staging row (o-local) 0..63
    const int c4   = (tid & 3) * 16; // staging col base (t/k-local)

    f32x4v av[4], bv[4];
#pragma unroll
    for (int p = 0; p < 4; ++p) {
        av[p] = *(const f32x4v*)&wk[(size_t)r * 1024 + t0 + c4 + p * 4];
        bv[p] = *(const f32x4v*)&wq[(size_t)r * 1024 + k0 + c4 + p * 4];
    }

    floatx4 acc[2][2];
#pragma unroll
    for (int i = 0; i < 2; ++i)
#pragma unroll
        for (int j = 0; j < 2; ++j) acc[i][j] = (floatx4)0.0f;

    for (int o0 = 0; o0 < 1024; o0 += 64) {
        if (o0) __syncthreads();     // prev chunk's frag reads done
#pragma unroll
        for (int p = 0; p < 4; ++p)
#pragma unroll
            for (int j = 0; j < 4; ++j) {
                TtA[c4 + p * 4 + j][r] = av[p][j];
                TtB[c4 + p * 4 + j][r] = bv[p][j];
            }
        __syncthreads();             // chunk published
        if (o0 + 64 < 1024) {        // prefetch next chunk (hides under work)
#pragma unroll
            for (int p = 0; p < 4; ++p) {
                av[p] = *(const f32x4v*)
                    &wk[(size_t)(o0 + 64 + r) * 1024 + t0 + c4 + p * 4];
                bv[p] = *(const f32x4v*)
                    &wq[(size_t)(o0 + 64 + r) * 1024 + k0 + c4 + p * 4];
            }
        }
#pragma unroll
        for (int s = 0; s < 2; ++s) {   // two 32-deep MFMA k-slices
            short8 aH[2], aL[2], bH[2], bL[2];
#pragma unroll
            for (int mt = 0; mt < 2; ++mt) {
                const int rowA = wm * 32 + mt * 16 + lm;
                const int rowB = wn * 32 + mt * 16 + lm;
#pragma unroll
                for (int e = 0; e < 8; ++e) {
                    const float fa = TtA[rowA][s * 32 + quad * 8 + e];
                    const unsigned short ha = f32_to_bf16(fa);
                    union { unsigned u; float f; } ca; ca.u = (unsigned)ha << 16;
                    aH[mt][e] = (short)ha;
                    aL[mt][e] = (short)f32_to_bf16(fa - ca.f);
                    const float fb = TtB[rowB][s * 32 + quad * 8 + e];
                    const unsigned short hb = f32_to_bf16(fb);
                    union { unsigned u; float f; } cb; cb.u = (unsigned)hb << 16;
                    bH[mt][e] = (short)hb;
                    bL[mt][e] = (short)f32_to_bf16(fb - cb.f);
                }
            }
#pragma unroll
            for (int mt = 0; mt < 2; ++mt)
#pragma unroll
                for (int nt = 0; nt < 2; ++nt) {
                    acc[mt][nt] = __builtin_amdgcn_mfma_f32_16x16x32_bf16(
                        aH[mt], bH[nt], acc[mt][nt], 0, 0, 0);
                    acc[mt][nt] = __builtin_amdgcn_mfma_f32_16x16x32_bf16(
                        aL[mt], bH[nt], acc[mt][nt], 0, 0, 0);
                    acc[mt][nt] = __builtin_amdgcn_mfma_f32_16x16x32_bf16(
                        aH[mt], bL[nt], acc[mt][nt], 0, 0, 0);
                }
        }
    }
    // epilogue: D row = quad*4 + rr, col = lm (m89/m91 mapping, R14-validated)
#pragma unroll
    for (int mt = 0; mt < 2; ++mt)
#pragma unroll
        for (int nt = 0; nt < 2; ++nt)
#pragma unroll
            for (int rr = 0; rr < 4; ++rr) {
                const int row = t0 + wm * 32 + mt * 16 + quad * 4 + rr;
                const int col = k0 + wn * 32 + nt * 16 + lm;
                Mp[(size_t)row * 1024 + col] = f32_to_bf16(acc[mt][nt][rr]);
            }
}

// ---- cvt dispatch: pure streaming converts (3X + Wv) + rowsum zero -------
#define CVT_BLOCKS 25608   // (3*2097152 + 262144 + 2048) / 256

__global__ __launch_bounds__(256) void cvt_all(
    const float* __restrict__ q, const float* __restrict__ k,
    const float* __restrict__ v, const float* __restrict__ wv,
    unsigned short* __restrict__ Xq, unsigned short* __restrict__ Xk,
    unsigned short* __restrict__ Xv, unsigned short* __restrict__ Wv,
    float* __restrict__ rowsum) {
    const long NTE4 = 2097152;  // 8192*1024/4
    const long NW4  = 262144;   // 1024*1024/4
    long i = (long)blockIdx.x * 256 + threadIdx.x;
    const float* src;
    unsigned short* dst;
    long j;
    if (i < 3 * NTE4) {
        int a = (int)(i / NTE4); j = i - (long)a * NTE4;
        src = a == 0 ? q : a == 1 ? k : v;
        dst = a == 0 ? Xq : a == 1 ? Xk : Xv;
    } else {
        i -= 3 * NTE4;
        if (i < NW4) {
            src = wv; dst = Wv; j = i;
        } else {
            i -= NW4;           // 2048 groups -> rowsum[0..8191] = 0
            if (i < 2048) ((f32x4v*)rowsum)[i] = (f32x4v)0.0f;
            return;
        }
    }
    f32x4v f = ((const f32x4v*)src)[j];
    u16x4 o;
#pragma unroll
    for (int t = 0; t < 4; ++t) o[t] = f32_to_bf16(f[t]);
    ((u16x4*)dst)[j] = o;
}

// ===========================================================================
// 128x128 body (proj + pv: proven 942 TF structure)
// ===========================================================================
#define BM 128
#define BN 128
#define BK 64

// EPI: 0 = store bf16; 2 = store fp32 x / rowsum[row]
template <int EPI>
__device__ __forceinline__ void gemm_body(
    const unsigned short* __restrict__ A, const unsigned short* __restrict__ B,
    void* __restrict__ Cv, int lda, int ldb, int ldc, int K, float scale,
    float* __restrict__ rowsum, int m0, int n0) {
    __shared__ unsigned short As[BM * BK];
    __shared__ unsigned short Bs[BN * BK];

    const int tid  = threadIdx.x;
    const int wave = tid >> 6;
    const int lane = tid & 63;
    const int lm   = lane & 15;
    const int quad = lane >> 4;
    const int wm   = wave >> 1;
    const int wn   = wave & 1;

    const int srow8 = lane >> 3;
    const int gcol  = ((lane & 7) ^ srow8) * 8;

    floatx4 acc[4][4];
#pragma unroll
    for (int i = 0; i < 4; ++i)
#pragma unroll
        for (int j = 0; j < 4; ++j) acc[i][j] = (floatx4)0.0f;

    for (int k0 = 0; k0 < K; k0 += BK) {
#pragma unroll
        for (int i = 0; i < 4; ++i) {
            const int rbase = wave * 32 + i * 8;
            G2L(A + (size_t)(m0 + rbase + srow8) * lda + k0 + gcol,
                &As[rbase * BK]);
            G2L(B + (size_t)(n0 + rbase + srow8) * ldb + k0 + gcol,
                &Bs[rbase * BK]);
        }
        __syncthreads();

#pragma unroll
        for (int s = 0; s < 2; ++s) {
            short8 af[4], bf[4];
#pragma unroll
            for (int t = 0; t < 4; ++t) {
                const int cs = ((s * 4 + quad) ^ (lm & 7)) * 8;
                af[t] = *(const short8*)&As[(wm * 64 + t * 16 + lm) * BK + cs];
                bf[t] = *(const short8*)&Bs[(wn * 64 + t * 16 + lm) * BK + cs];
            }
#pragma unroll
            for (int mt = 0; mt < 4; ++mt)
#pragma unroll
                for (int nt = 0; nt < 4; ++nt)
                    acc[mt][nt] = __builtin_amdgcn_mfma_f32_16x16x32_bf16(
                        af[mt], bf[nt], acc[mt][nt], 0, 0, 0);
        }
        __syncthreads();
    }

    // epilogue: D row = quad*4 + reg, col = lane&15 (m89/m91 mapping)
    if constexpr (EPI == 0) {
        unsigned short* C = (unsigned short*)Cv;
#pragma unroll
        for (int mt = 0; mt < 4; ++mt)
#pragma unroll
            for (int nt = 0; nt < 4; ++nt)
#pragma unroll
                for (int r = 0; r < 4; ++r) {
                    const int row = m0 + wm * 64 + mt * 16 + quad * 4 + r;
                    const int col = n0 + wn * 64 + nt * 16 + lm;
                    C[(size_t)row * ldc + col] = f32_to_bf16(acc[mt][nt][r]);
                }
    } else if constexpr (EPI == 2) {
        float* C = (float*)Cv;
#pragma unroll
        for (int mt = 0; mt < 4; ++mt)
#pragma unroll
            for (int r = 0; r < 4; ++r) {
                const int row = m0 + wm * 64 + mt * 16 + quad * 4 + r;
                const float inv = 1.0f / rowsum[row];
#pragma unroll
                for (int nt = 0; nt < 4; ++nt) {
                    const int col = n0 + wn * 64 + nt * 16 + lm;
                    C[(size_t)row * ldc + col] = acc[mt][nt][r] * inv;
                }
            }
    }
}

// ---- merged projections: z=0 q''=Xq@Mp^T ; z=1 vT=Wv@Xv^T (roles swapped) -
__global__ __launch_bounds__(256, 4) void proj_kernel(
    const unsigned short* __restrict__ Xq, const unsigned short* __restrict__ Mp,
    unsigned short* __restrict__ qb,
    const unsigned short* __restrict__ Wv, const unsigned short* __restrict__ Xv,
    unsigned short* __restrict__ vT) {
    const int z = blockIdx.z;
    const unsigned short* A = z == 0 ? Xq : Wv;
    const unsigned short* B = z == 0 ? Mp : Xv;
    unsigned short* C = z == 0 ? qb : vT;
    int m0, n0, ldc;
    if (z == 0) { m0 = blockIdx.x * BM; n0 = blockIdx.y * BN; ldc = 1024; }
    else        { m0 = blockIdx.y * BM; n0 = blockIdx.x * BN; ldc = 8192; }
    gemm_body<0>(A, B, C, 1024, 1024, ldc, 1024, 1.0f, nullptr, m0, n0);
}

__global__ __launch_bounds__(256, 4) void pv_kernel(
    const unsigned short* __restrict__ Sc, const unsigned short* __restrict__ vT,
    float* __restrict__ out, float* __restrict__ rowsum) {
    const long z = blockIdx.z;
    gemm_body<2>(Sc + z * 2048 * 2048, vT + z * 2048,
                 out + z * 2048 * 1024, 2048, 8192, 1024, 2048,
                 1.0f, rowsum + z * 2048,
                 blockIdx.x * BM, blockIdx.y * BN);
}

// ===========================================================================
// 256x256 8-phase body (scores only: 256 blocks = perfect 1/CU packing)
// ===========================================================================
template <int EPI>
__device__ __forceinline__ void gemm256_body(
    const unsigned short* __restrict__ A, const unsigned short* __restrict__ B,
    void* __restrict__ Cv, int lda, int ldb, int ldc, int K, float scale,
    float* __restrict__ rowsum, int m0, int n0) {
    __shared__ unsigned short As[2][256 * 64];
    __shared__ unsigned short Bs[2][256 * 64];

    const int tid   = threadIdx.x;
    const int wave  = tid >> 6;      // 0..7
    const int lane  = tid & 63;
    const int lm    = lane & 15;     // MFMA row-in-frag
    const int quad  = lane >> 4;     // 0..3
    const int wm    = wave >> 2;     // 0..1  (wave tile 2x4)
    const int wn    = wave & 3;      // 0..3
    const int srow8 = lane >> 3;
    const int gcol  = ((lane & 7) ^ srow8) * 8;  // pre-swizzled global col
    const int KT    = K >> 6;

#define STAGE_A(buf, half, kcol) do { \
        const int r0_ = (half) * 128 + wave * 8; \
        G2L(A + (size_t)(m0 + r0_ + srow8) * lda + (kcol) + gcol, \
            &As[buf][r0_ * 64]); \
        G2L(A + (size_t)(m0 + r0_ + 64 + srow8) * lda + (kcol) + gcol, \
            &As[buf][(r0_ + 64) * 64]); \
    } while (0)
#define STAGE_B(buf, half, kcol) do { \
        const int r0_ = (half) * 128 + wave * 8; \
        G2L(B + (size_t)(n0 + r0_ + srow8) * ldb + (kcol) + gcol, \
            &Bs[buf][r0_ * 64]); \
        G2L(B + (size_t)(n0 + r0_ + 64 + srow8) * ldb + (kcol) + gcol, \
            &Bs[buf][(r0_ + 64) * 64]); \
    } while (0)

    floatx4 acc[8][4];
#pragma unroll
    for (int i = 0; i < 8; ++i)
#pragma unroll
        for (int j = 0; j < 4; ++j) acc[i][j] = (floatx4)0.0f;

    // prologue: tile0 -> buf0, tile1 -> buf1 (8 loads each); vmcnt(8) => t0 landed
    STAGE_A(0, 0, 0); STAGE_A(0, 1, 0); STAGE_B(0, 0, 0); STAGE_B(0, 1, 0);
    if (KT > 1) {
        STAGE_A(1, 0, 64); STAGE_A(1, 1, 64);
        STAGE_B(1, 0, 64); STAGE_B(1, 1, 64);
        asm volatile("s_waitcnt vmcnt(8)" ::: "memory");
    } else {
        asm volatile("s_waitcnt vmcnt(0)" ::: "memory");
    }
    BAR();

    short8 aA[2][4];   // A half m0  (Q1, Q4)
    short8 aM[2][4];   // A half m1  (Q2, Q3)
    short8 bB[2][2];   // B half: n0 during Q1/Q2, overwritten with n1 at S3

    for (int kt = 0; kt < KT; ++kt) {
        const int b = kt & 1;
        const unsigned short* Ab = As[b];
        const unsigned short* Bb = Bs[b];

        // ---- S1: reads for Q1 (aA + bB=n0), then read-ahead aM (Q2) ----
#pragma unroll
        for (int s = 0; s < 2; ++s) {
            const int cs = ((s * 4 + quad) ^ (lm & 7)) * 8;
#pragma unroll
            for (int mt = 0; mt < 4; ++mt)
                aA[s][mt] = *(const short8*)&Ab[(wm * 128 + mt * 16 + lm) * 64 + cs];
#pragma unroll
            for (int nt = 0; nt < 2; ++nt)
                bB[s][nt] = *(const short8*)&Bb[(wn * 64 + nt * 16 + lm) * 64 + cs];
        }
#pragma unroll
        for (int s = 0; s < 2; ++s) {
            const int cs = ((s * 4 + quad) ^ (lm & 7)) * 8;
#pragma unroll
            for (int mt = 0; mt < 4; ++mt)
                aM[s][mt] = *(const short8*)&Ab[(wm * 128 + 64 + mt * 16 + lm) * 64 + cs];
        }
        BAR();
        // P1: MFMA Q1 (compiler waits counted lgkm; aM stays in flight)
        __builtin_amdgcn_s_setprio(1);
#pragma unroll
        for (int s = 0; s < 2; ++s)
#pragma unroll
            for (int mt = 0; mt < 4; ++mt)
#pragma unroll
                for (int nt = 0; nt < 2; ++nt)
                    acc[mt][nt] = __builtin_amdgcn_mfma_f32_16x16x32_bf16(
                        aA[s][mt], bB[s][nt], acc[mt][nt], 0, 0, 0);
        __builtin_amdgcn_s_setprio(0);
        BAR();

        // ---- S2: (no reads, no stages) ----
        BAR();
        // P2: MFMA Q2
        __builtin_amdgcn_s_setprio(1);
#pragma unroll
        for (int s = 0; s < 2; ++s)
#pragma unroll
            for (int mt = 0; mt < 4; ++mt)
#pragma unroll
                for (int nt = 0; nt < 2; ++nt)
                    acc[4 + mt][nt] = __builtin_amdgcn_mfma_f32_16x16x32_bf16(
                        aM[s][mt], bB[s][nt], acc[4 + mt][nt], 0, 0, 0);
        __builtin_amdgcn_s_setprio(0);
        BAR();

        // ---- S3: read bB=n1 (A-reads all done by P2-close); stage A(t+2) ----
#pragma unroll
        for (int s = 0; s < 2; ++s) {
            const int cs = ((s * 4 + quad) ^ (lm & 7)) * 8;
#pragma unroll
            for (int nt = 0; nt < 2; ++nt)
                bB[s][nt] = *(const short8*)&Bb[(wn * 64 + 32 + nt * 16 + lm) * 64 + cs];
        }
        if (kt + 2 < KT) { STAGE_A(b, 0, (kt + 2) * 64); STAGE_A(b, 1, (kt + 2) * 64); }
        BAR();
        // P3: MFMA Q3
        __builtin_amdgcn_s_setprio(1);
#pragma unroll
        for (int s = 0; s < 2; ++s)
#pragma unroll
            for (int mt = 0; mt < 4; ++mt)
#pragma unroll
                for (int nt = 0; nt < 2; ++nt)
                    acc[4 + mt][2 + nt] = __builtin_amdgcn_mfma_f32_16x16x32_bf16(
                        aM[s][mt], bB[s][nt], acc[4 + mt][2 + nt], 0, 0, 0);
        __builtin_amdgcn_s_setprio(0);
        BAR();

        // ---- S4: stage B(t+2) (B-reads all done by P3-close) ----
        if (kt + 2 < KT) { STAGE_B(b, 0, (kt + 2) * 64); STAGE_B(b, 1, (kt + 2) * 64); }
        BAR();
        // P4: MFMA Q4; then counted vmcnt => tile t+1 landed; publish barrier
        __builtin_amdgcn_s_setprio(1);
#pragma unroll
        for (int s = 0; s < 2; ++s)
#pragma unroll
            for (int mt = 0; mt < 4; ++mt)
#pragma unroll
                for (int nt = 0; nt < 2; ++nt)
                    acc[mt][2 + nt] = __builtin_amdgcn_mfma_f32_16x16x32_bf16(
                        aA[s][mt], bB[s][nt], acc[mt][2 + nt], 0, 0, 0);
        __builtin_amdgcn_s_setprio(0);
        if (kt + 2 < KT) {
            asm volatile("s_waitcnt vmcnt(8)" ::: "memory");
        } else if (kt + 1 < KT) {
            asm volatile("s_waitcnt vmcnt(0)" ::: "memory");
        }
        BAR();
    }
#undef STAGE_A
#undef STAGE_B

    // epilogue: D row = quad*4 + reg, col = lane&15 (m89/m91 mapping)
    if constexpr (EPI == 1) {
        unsigned short* C = (unsigned short*)Cv;
        float psum[8][4];
#pragma unroll
        for (int f = 0; f < 8; ++f)
#pragma unroll
            for (int r = 0; r < 4; ++r) psum[f][r] = 0.0f;
#pragma unroll
        for (int f = 0; f < 8; ++f)
#pragma unroll
            for (int g = 0; g < 4; ++g)
#pragma unroll
                for (int r = 0; r < 4; ++r) {
                    const int row = m0 + wm * 128 + f * 16 + quad * 4 + r;
                    const int col = n0 + wn * 64 + g * 16 + lm;
                    const float p = __expf(acc[f][g][r] * scale);
                    psum[f][r] += p;
                    C[(size_t)row * ldc + col] = f32_to_bf16(p);
                }
#pragma unroll
        for (int off = 1; off <= 8; off <<= 1)
#pragma unroll
            for (int f = 0; f < 8; ++f)
#pragma unroll
                for (int r = 0; r < 4; ++r)
                    psum[f][r] += __shfl_xor(psum[f][r], off);
        if (lm == 0) {
#pragma unroll
            for (int f = 0; f < 8; ++f)
#pragma unroll
                for (int r = 0; r < 4; ++r)
                    atomicAdd(&rowsum[m0 + wm * 128 + f * 16 + quad * 4 + r],
                              psum[f][r]);
        }
    }
}

__global__ __launch_bounds__(512, 2) void scores256_kernel(
    const unsigned short* __restrict__ qb, const unsigned short* __restrict__ Xk,
    unsigned short* __restrict__ Sc, float* __restrict__ rowsum) {
    const long z = blockIdx.z;
    gemm256_body<1>(qb + z * 2048 * 1024, Xk + z * 2048 * 1024,
                    Sc + z * 2048 * 2048, 1024, 1024, 2048, 1024,
                    1.0f / 32.0f, rowsum + z * 2048,
                    blockIdx.x * 256, blockIdx.y * 256);
}

// ---------------------------------------------------------------------------
extern "C" void kernel_launch(void* const* d_in, const int* in_sizes, int n_in,
                              void* d_out, int out_size, void* d_ws, size_t ws_size,
                              hipStream_t stream) {
    const float* q_in = (const float*)d_in[0];
    const float* k_in = (const float*)d_in[1];
    const float* v_in = (const float*)d_in[2];
    const float* Qw_f = (const float*)d_in[3];
    const float* Kw_f = (const float*)d_in[4];
    const float* Vw_f = (const float*)d_in[5];
    float* out = (float*)d_out;

    const int Bb = 4, S = 2048, E = 1024;
    const size_t TOK = (size_t)Bb * S;       // 8192
    const size_t NTE = TOK * E;              // 8,388,608
    const size_t NW  = (size_t)E * E;        // 1,048,576

    unsigned short* ws = (unsigned short*)d_ws;
    unsigned short* Xq = ws;            // [8192,1024]
    unsigned short* Xk = Xq + NTE;
    unsigned short* Xv = Xk + NTE;
    unsigned short* Wv = Xv + NTE;      // [1024,1024]
    unsigned short* Mp = Wv + NW;       // [1024 t][1024 k] = Wk^T Wq (NT rows)
    unsigned short* qb = Mp + NW;       // [8192,1024]  q'' = Xq @ Mp^T
    unsigned short* vT = qb + NTE;      // [1024 e][8192 tok]
    unsigned short* Sc = vT + NTE;      // [4][2048][2048] exp-scores
    float* rowsum = (float*)(Sc + (size_t)Bb * S * S);  // [4][2048]

    // 1) Mp = Wk^T Wq (dedicated pipelined kernel, 256 blocks, ~12us)
    mp_kernel<<<256, 256, 0, stream>>>(Kw_f, Qw_f, Mp);

    // 2) streaming converts (3X + Wv) + rowsum zero
    cvt_all<<<CVT_BLOCKS, 256, 0, stream>>>(
        q_in, k_in, v_in, Vw_f, Xq, Xk, Xv, Wv, rowsum);

    // 3) q'' and vT, one dispatch (1024 blocks = perfect 4/CU packing)
    proj_kernel<<<dim3(TOK / BM, E / BN, 2), 256, 0, stream>>>(
        Xq, Mp, qb, Wv, Xv, vT);

    // 4) P = exp(q'' Xk^T / 32) + fp32 rowsums (256 blocks, perfect packing)
    scores256_kernel<<<dim3(S / 256, S / 256, 4), 512, 0, stream>>>(
        qb, Xk, Sc, rowsum);

    // 5) out = (P @ v) / rowsum  (128^2 body, 512 blocks, 4/CU)
    pv_kernel<<<dim3(S / BM, E / BN, 4), 256, 0, stream>>>(
        Sc, vT, out, rowsum);
}